// Round 2
// baseline (687.069 us; speedup 1.0000x reference)
//
#include <hip/hip_runtime.h>

// EEGGraphClf graph-loss, fused single pass over A. B=64, N=1024, D=16.
//
// loss[b] = 0.2 * sum_{n,j} A[n,j]*(||f_n||^2 - f_n.f_j) / N^2
//         - 0.1 * sum_n log(deg_n + 1e-12) / N
//         + 0.1 * sum_{n,j} A[n,j]^2 / N^2
//
// 16 blocks/batch, block = 64 rows x 1024 cols. Thread t owns cols 4t..4t+3
// (features in 16 float4 VGPRs). A read once, coalesced float4, 4-deep
// prefetch, ZERO barriers in the main loop (deg via 2x shfl + masked LDS
// write into padded [64][65] group-partials, reduced once at the end).

#define NN      1024
#define DD      16
#define ROWS    64
#define TPB     256
#define PF      4
#define SMOOTHR 0.2f
#define DEGRR   0.1f
#define SPARSR  0.1f
#define EPSV    1e-12f

__global__ __launch_bounds__(TPB, 4)
void graph_loss_kernel(const float* __restrict__ A,
                       const float* __restrict__ F,
                       float* __restrict__ out) {
    __shared__ float fn_lds[ROWS][DD];   // 4 KB, rows 16B-aligned (broadcast b128 reads)
    __shared__ float fn2_lds[ROWS];      // ||f_n||^2
    __shared__ float degq[ROWS][65];     // 16.6 KB: 64 group partials/row, pad 65 (bank-safe)
    __shared__ float wred[4][2];

    const int tid = threadIdx.x;
    const int bid = blockIdx.x;
    const int b   = bid >> 4;
    const int n0  = (bid & 15) * ROWS;

    const float* __restrict__ Fb = F + (size_t)b * NN * DD;
    const float* __restrict__ Ab = A + ((size_t)b * NN + n0) * NN;

    // ---- column features: fj[jj][q] = F[4t+jj][4q..4q+3], 16 float4 = 64 VGPR ----
    float4 fj[4][4];
    {
        const float* p = Fb + (size_t)(4 * tid) * DD;
        #pragma unroll
        for (int jj = 0; jj < 4; ++jj)
            #pragma unroll
            for (int q = 0; q < 4; ++q)
                fj[jj][q] = *(const float4*)(p + jj * DD + 4 * q);
    }

    // ---- stage this slab's row features (coalesced float4) ----
    {
        const int r = tid >> 2, q = tid & 3;
        *(float4*)&fn_lds[r][4 * q] =
            *(const float4*)(Fb + (size_t)(n0 + r) * DD + 4 * q);
    }
    __syncthreads();
    if (tid < ROWS) {
        float s = 0.f;
        #pragma unroll
        for (int d = 0; d < DD; ++d) s += fn_lds[tid][d] * fn_lds[tid][d];
        fn2_lds[tid] = s;
    }
    __syncthreads();

    float sm = 0.f, sq = 0.f;

    const float* __restrict__ arow = Ab + 4 * tid;
    const int  g       = tid >> 2;
    const bool deglane = (tid & 3) == 0;

    auto process = [&](const float4 a, const int r) {
        // row-degree group partial: this thread's 4 cols, + 2-step shfl = 16 cols
        float s = (a.x + a.y) + (a.z + a.w);
        s += __shfl_xor(s, 1);
        s += __shfl_xor(s, 2);
        if (deglane) degq[r][g] = s;

        sq += a.x * a.x + a.y * a.y + a.z * a.z + a.w * a.w;

        float dt0 = 0.f, dt1 = 0.f, dt2 = 0.f, dt3 = 0.f;
        #pragma unroll
        for (int q = 0; q < 4; ++q) {
            const float4 f = *(const float4*)&fn_lds[r][4 * q];  // broadcast
            dt0 += fj[0][q].x * f.x + fj[0][q].y * f.y + fj[0][q].z * f.z + fj[0][q].w * f.w;
            dt1 += fj[1][q].x * f.x + fj[1][q].y * f.y + fj[1][q].z * f.z + fj[1][q].w * f.w;
            dt2 += fj[2][q].x * f.x + fj[2][q].y * f.y + fj[2][q].z * f.z + fj[2][q].w * f.w;
            dt3 += fj[3][q].x * f.x + fj[3][q].y * f.y + fj[3][q].z * f.z + fj[3][q].w * f.w;
        }
        const float fn2 = fn2_lds[r];
        sm += a.x * (fn2 - dt0) + a.y * (fn2 - dt1)
            + a.z * (fn2 - dt2) + a.w * (fn2 - dt3);
    };

    // ---- main loop: 4-deep prefetch, no barriers ----
    float4 buf[PF];
    #pragma unroll
    for (int i = 0; i < PF; ++i)
        buf[i] = *(const float4*)(arow + (size_t)i * NN);

    #pragma unroll 1
    for (int rb = 0; rb < ROWS - PF; rb += PF) {
        #pragma unroll
        for (int k = 0; k < PF; ++k) {
            const float4 a = buf[k];
            buf[k] = *(const float4*)(arow + (size_t)(rb + k + PF) * NN);
            process(a, rb + k);
        }
    }
    #pragma unroll
    for (int k = 0; k < PF; ++k)
        process(buf[k], ROWS - PF + k);

    // ---- finalize degrees (single barrier) ----
    __syncthreads();
    float lg = 0.f;
    if (tid < ROWS) {
        float s = 0.f;
        #pragma unroll 1
        for (int i = 0; i < ROWS; ++i) s += degq[tid][i];  // 2 lanes/bank: free
        lg = logf(s + EPSV);
    }

    // ---- block reduction: sm/sq across 4 waves; lg lives wholly in wave 0 ----
    #pragma unroll
    for (int m = 1; m < 64; m <<= 1) {
        sm += __shfl_xor(sm, m);
        sq += __shfl_xor(sq, m);
        lg += __shfl_xor(lg, m);
    }
    const int w = tid >> 6;
    if ((tid & 63) == 0) { wred[w][0] = sm; wred[w][1] = sq; }
    __syncthreads();
    if (tid == 0) {
        float S = 0.f, Q = 0.f;
        #pragma unroll
        for (int i = 0; i < 4; ++i) { S += wred[i][0]; Q += wred[i][1]; }
        const float denom = (float)NN * (float)NN;
        const float contrib = SMOOTHR * S / denom
                            - DEGRR * lg / (float)NN
                            + SPARSR * Q / denom;
        atomicAdd(out + b, contrib);
    }
}

extern "C" void kernel_launch(void* const* d_in, const int* in_sizes, int n_in,
                              void* d_out, int out_size, void* d_ws, size_t ws_size,
                              hipStream_t stream) {
    const float* A = (const float*)d_in[0];   // out_adj [B,N,N]
    const float* F = (const float*)d_in[1];   // features [B,N,D]
    float* out = (float*)d_out;               // [B]

    const int B = out_size;                   // 64
    hipMemsetAsync(d_out, 0, (size_t)B * sizeof(float), stream);
    graph_loss_kernel<<<dim3(B * (NN / ROWS)), dim3(TPB), 0, stream>>>(A, F, out);
}

// Round 3
// 371.782 us; speedup vs baseline: 1.8480x; 1.8480x over previous
//
#include <hip/hip_runtime.h>

// EEGGraphClf graph-loss, fused single pass over A. B=64, N=1024, D=16.
//
// loss[b] = 0.2 * sum_{n,j} A[n,j]*(||f_n||^2 - f_n.f_j) / N^2
//         - 0.1 * sum_n log(deg_n + 1e-12) / N
//         + 0.1 * sum_{n,j} A[n,j]^2 / N^2
//
// 16 blocks/batch, block = 64 rows x 1024 cols. Thread t owns cols 4t..4t+3
// (features in 16 float4 VGPRs). A read once, coalesced float4, 4-deep
// prefetch in NAMED registers, zero barriers in the main loop.
//
// R2 lesson: __launch_bounds__(256,4) capped VGPRs so hard the fj tile
// spilled (VGPR=64, WRITE_SIZE=550MB of scratch). No occupancy clamp here:
// 2-3 blocks/CU with ~150 VGPR still keeps >=32KB/CU of loads in flight,
// which saturates HBM (need ~22KB at 900cyc latency, 24.6 GB/s/CU).

#define NN      1024
#define DD      16
#define ROWS    64
#define TPB     256
#define SMOOTHR 0.2f
#define DEGRR   0.1f
#define SPARSR  0.1f
#define EPSV    1e-12f

__global__ __launch_bounds__(TPB)
void graph_loss_kernel(const float* __restrict__ A,
                       const float* __restrict__ F,
                       float* __restrict__ out) {
    __shared__ float fn_lds[ROWS][DD];   // 4 KB, rows 16B-aligned (broadcast b128 reads)
    __shared__ float fn2_lds[ROWS];      // ||f_n||^2
    __shared__ float degq[ROWS][65];     // 16.6 KB: 64 group partials/row, pad 65 (bank-safe)
    __shared__ float wred[4][2];

    const int tid = threadIdx.x;
    const int bid = blockIdx.x;
    const int b   = bid >> 4;
    const int n0  = (bid & 15) * ROWS;

    const float* __restrict__ Fb = F + (size_t)b * NN * DD;
    const float* __restrict__ Ab = A + ((size_t)b * NN + n0) * NN;

    // ---- column features: fj[jj][q] = F[4t+jj][4q..4q+3], 16 float4 = 64 VGPR ----
    float4 fj[4][4];
    {
        const float* p = Fb + (size_t)(4 * tid) * DD;
        #pragma unroll
        for (int jj = 0; jj < 4; ++jj)
            #pragma unroll
            for (int q = 0; q < 4; ++q)
                fj[jj][q] = *(const float4*)(p + jj * DD + 4 * q);
    }

    // ---- stage this slab's row features (coalesced float4) ----
    {
        const int r = tid >> 2, q = tid & 3;
        *(float4*)&fn_lds[r][4 * q] =
            *(const float4*)(Fb + (size_t)(n0 + r) * DD + 4 * q);
    }
    __syncthreads();
    if (tid < ROWS) {
        float s = 0.f;
        #pragma unroll
        for (int d = 0; d < DD; ++d) s += fn_lds[tid][d] * fn_lds[tid][d];
        fn2_lds[tid] = s;
    }
    __syncthreads();

    float sm = 0.f, sq = 0.f;

    const float* __restrict__ arow = Ab + 4 * tid;
    const int  g       = tid >> 2;
    const bool deglane = (tid & 3) == 0;

    auto process = [&](const float4 a, const int r) {
        // row-degree group partial: this thread's 4 cols, + 2-step shfl = 16 cols
        float s = (a.x + a.y) + (a.z + a.w);
        s += __shfl_xor(s, 1);
        s += __shfl_xor(s, 2);
        if (deglane) degq[r][g] = s;

        sq += a.x * a.x + a.y * a.y + a.z * a.z + a.w * a.w;

        float dt0 = 0.f, dt1 = 0.f, dt2 = 0.f, dt3 = 0.f;
        #pragma unroll
        for (int q = 0; q < 4; ++q) {
            const float4 f = *(const float4*)&fn_lds[r][4 * q];  // broadcast
            dt0 += fj[0][q].x * f.x + fj[0][q].y * f.y + fj[0][q].z * f.z + fj[0][q].w * f.w;
            dt1 += fj[1][q].x * f.x + fj[1][q].y * f.y + fj[1][q].z * f.z + fj[1][q].w * f.w;
            dt2 += fj[2][q].x * f.x + fj[2][q].y * f.y + fj[2][q].z * f.z + fj[2][q].w * f.w;
            dt3 += fj[3][q].x * f.x + fj[3][q].y * f.y + fj[3][q].z * f.z + fj[3][q].w * f.w;
        }
        const float fn2 = fn2_lds[r];
        sm += a.x * (fn2 - dt0) + a.y * (fn2 - dt1)
            + a.z * (fn2 - dt2) + a.w * (fn2 - dt3);
    };

    // ---- main loop: 4-deep prefetch in NAMED regs, no barriers ----
    #define LOADR(r) (*(const float4*)(arow + (size_t)(r) * NN))
    float4 a0 = LOADR(0), a1 = LOADR(1), a2 = LOADR(2), a3 = LOADR(3);

    #pragma unroll 1
    for (int rb = 0; rb < ROWS - 4; rb += 4) {
        const float4 t0 = a0, t1 = a1, t2 = a2, t3 = a3;
        a0 = LOADR(rb + 4);
        a1 = LOADR(rb + 5);
        a2 = LOADR(rb + 6);
        a3 = LOADR(rb + 7);
        process(t0, rb + 0);
        process(t1, rb + 1);
        process(t2, rb + 2);
        process(t3, rb + 3);
    }
    process(a0, ROWS - 4);
    process(a1, ROWS - 3);
    process(a2, ROWS - 2);
    process(a3, ROWS - 1);
    #undef LOADR

    // ---- finalize degrees (single barrier) ----
    __syncthreads();
    float lg = 0.f;
    if (tid < ROWS) {
        float s = 0.f;
        #pragma unroll 1
        for (int i = 0; i < ROWS; ++i) s += degq[tid][i];  // stride 65: 2 lanes/bank, free
        lg = logf(s + EPSV);
    }

    // ---- block reduction: sm/sq across 4 waves; lg lives wholly in wave 0 ----
    #pragma unroll
    for (int m = 1; m < 64; m <<= 1) {
        sm += __shfl_xor(sm, m);
        sq += __shfl_xor(sq, m);
        lg += __shfl_xor(lg, m);
    }
    const int w = tid >> 6;
    if ((tid & 63) == 0) { wred[w][0] = sm; wred[w][1] = sq; }
    __syncthreads();
    if (tid == 0) {
        float S = 0.f, Q = 0.f;
        #pragma unroll
        for (int i = 0; i < 4; ++i) { S += wred[i][0]; Q += wred[i][1]; }
        const float denom = (float)NN * (float)NN;
        const float contrib = SMOOTHR * S / denom
                            - DEGRR * lg / (float)NN
                            + SPARSR * Q / denom;
        atomicAdd(out + b, contrib);
    }
}

extern "C" void kernel_launch(void* const* d_in, const int* in_sizes, int n_in,
                              void* d_out, int out_size, void* d_ws, size_t ws_size,
                              hipStream_t stream) {
    const float* A = (const float*)d_in[0];   // out_adj [B,N,N]
    const float* F = (const float*)d_in[1];   // features [B,N,D]
    float* out = (float*)d_out;               // [B]

    const int B = out_size;                   // 64
    hipMemsetAsync(d_out, 0, (size_t)B * sizeof(float), stream);
    graph_loss_kernel<<<dim3(B * (NN / ROWS)), dim3(TPB), 0, stream>>>(A, F, out);
}

// Round 5
// 366.471 us; speedup vs baseline: 1.8748x; 1.0145x over previous
//
#include <hip/hip_runtime.h>

// EEGGraphClf graph-loss, fused single pass over A. B=64, N=1024, D=16.
//
// loss[b] = 0.2 * sum_{n,j} A[n,j]*(||f_n||^2 - f_n.f_j) / N^2
//         - 0.1 * sum_n log(deg_n + 1e-12) / N
//         + 0.1 * sum_{n,j} A[n,j]^2 / N^2
//
// 16 blocks/batch, block = 64 rows x 1024 cols, 256 threads. Thread t owns
// cols 4t..4t+3 (fj in 16 float4 = 64 VGPR). A read once, coalesced
// nontemporal float4, 2-deep named-register prefetch, zero barriers in the
// main loop.
//
// R3 lesson: ~119us kernel, suspected >128 VGPR -> 2 waves/SIMD cliff ->
// latency-bound. This round: f_n comes in via UNIFORM loads (scalarizes to
// s_load_dwordx4 -> SGPRs, no LDS, no VGPR cost), prefetch trimmed to 2.
// R4 lesson: __builtin_nontemporal_load needs a clang ext_vector type, not
// HIP's float4 struct -> vf4 typedef below.

#define NN      1024
#define DD      16
#define ROWS    64
#define TPB     256
#define SMOOTHR 0.2f
#define DEGRR   0.1f
#define SPARSR  0.1f
#define EPSV    1e-12f

typedef float vf4 __attribute__((ext_vector_type(4)));

__global__ __launch_bounds__(TPB)
void graph_loss_kernel(const float* __restrict__ A,
                       const float* __restrict__ F,
                       float* __restrict__ out) {
    __shared__ float fn2_lds[ROWS];      // ||f_n||^2, broadcast b32 reads
    __shared__ float degq[ROWS][65];     // 16.6 KB deg group-partials, pad 65
    __shared__ float wred[4][2];

    const int tid = threadIdx.x;
    const int bid = blockIdx.x;
    const int b   = bid >> 4;
    const int n0  = (bid & 15) * ROWS;

    const float* __restrict__ Fb = F + (size_t)b * NN * DD;
    const float* __restrict__ Ab = A + ((size_t)b * NN + n0) * NN;

    // ---- column features: fj[jj][q] = F[4t+jj][4q..4q+3], 16 vf4 = 64 VGPR ----
    vf4 fj[4][4];
    {
        const float* p = Fb + (size_t)(4 * tid) * DD;
        #pragma unroll
        for (int jj = 0; jj < 4; ++jj)
            #pragma unroll
            for (int q = 0; q < 4; ++q)
                fj[jj][q] = *(const vf4*)(p + jj * DD + 4 * q);
    }

    // ---- row norms ----
    if (tid < ROWS) {
        const float* p = Fb + (size_t)(n0 + tid) * DD;
        float s = 0.f;
        #pragma unroll
        for (int d = 0; d < DD; ++d) s += p[d] * p[d];
        fn2_lds[tid] = s;
    }
    __syncthreads();

    float sm = 0.f, sq = 0.f;

    const float* __restrict__ arow = Ab + 4 * tid;
    const int  g       = tid >> 2;
    const bool deglane = (tid & 3) == 0;

    // ---- main loop: 2-deep named prefetch, no barriers, f_n via uniform loads ----
    #define LOADR(r) __builtin_nontemporal_load((const vf4*)(arow + (size_t)(r) * NN))
    vf4 a0 = LOADR(0);
    vf4 a1 = LOADR(1);

    #pragma unroll 1
    for (int r = 0; r < ROWS; ++r) {
        const vf4 a = a0;
        a0 = a1;
        if (r + 2 < ROWS) a1 = LOADR(r + 2);   // uniform branch

        // wave-uniform row features -> scalar loads (SGPRs), no LDS, no VGPR
        const vf4* __restrict__ Fr = (const vf4*)(Fb + (size_t)(n0 + r) * DD);
        const vf4 f0 = Fr[0], f1 = Fr[1], f2 = Fr[2], f3 = Fr[3];
        const float fn2 = fn2_lds[r];          // same-address broadcast b32

        // row-degree group partial: 4 own cols + 2-step shfl = 16 cols
        float s = (a.x + a.y) + (a.z + a.w);
        s += __shfl_xor(s, 1);
        s += __shfl_xor(s, 2);
        if (deglane) degq[r][g] = s;

        sq += a.x * a.x + a.y * a.y + a.z * a.z + a.w * a.w;

        float dt0, dt1, dt2, dt3;
        dt0  = fj[0][0].x * f0.x + fj[0][0].y * f0.y + fj[0][0].z * f0.z + fj[0][0].w * f0.w;
        dt0 += fj[0][1].x * f1.x + fj[0][1].y * f1.y + fj[0][1].z * f1.z + fj[0][1].w * f1.w;
        dt0 += fj[0][2].x * f2.x + fj[0][2].y * f2.y + fj[0][2].z * f2.z + fj[0][2].w * f2.w;
        dt0 += fj[0][3].x * f3.x + fj[0][3].y * f3.y + fj[0][3].z * f3.z + fj[0][3].w * f3.w;
        dt1  = fj[1][0].x * f0.x + fj[1][0].y * f0.y + fj[1][0].z * f0.z + fj[1][0].w * f0.w;
        dt1 += fj[1][1].x * f1.x + fj[1][1].y * f1.y + fj[1][1].z * f1.z + fj[1][1].w * f1.w;
        dt1 += fj[1][2].x * f2.x + fj[1][2].y * f2.y + fj[1][2].z * f2.z + fj[1][2].w * f2.w;
        dt1 += fj[1][3].x * f3.x + fj[1][3].y * f3.y + fj[1][3].z * f3.z + fj[1][3].w * f3.w;
        dt2  = fj[2][0].x * f0.x + fj[2][0].y * f0.y + fj[2][0].z * f0.z + fj[2][0].w * f0.w;
        dt2 += fj[2][1].x * f1.x + fj[2][1].y * f1.y + fj[2][1].z * f1.z + fj[2][1].w * f1.w;
        dt2 += fj[2][2].x * f2.x + fj[2][2].y * f2.y + fj[2][2].z * f2.z + fj[2][2].w * f2.w;
        dt2 += fj[2][3].x * f3.x + fj[2][3].y * f3.y + fj[2][3].z * f3.z + fj[2][3].w * f3.w;
        dt3  = fj[3][0].x * f0.x + fj[3][0].y * f0.y + fj[3][0].z * f0.z + fj[3][0].w * f0.w;
        dt3 += fj[3][1].x * f1.x + fj[3][1].y * f1.y + fj[3][1].z * f1.z + fj[3][1].w * f1.w;
        dt3 += fj[3][2].x * f2.x + fj[3][2].y * f2.y + fj[3][2].z * f2.z + fj[3][2].w * f2.w;
        dt3 += fj[3][3].x * f3.x + fj[3][3].y * f3.y + fj[3][3].z * f3.z + fj[3][3].w * f3.w;

        sm += a.x * (fn2 - dt0) + a.y * (fn2 - dt1)
            + a.z * (fn2 - dt2) + a.w * (fn2 - dt3);
    }
    #undef LOADR

    // ---- finalize degrees (single barrier) ----
    __syncthreads();
    float lg = 0.f;
    if (tid < ROWS) {
        float s = 0.f;
        #pragma unroll 1
        for (int i = 0; i < ROWS; ++i) s += degq[tid][i];  // stride 65: 2 lanes/bank, free
        lg = logf(s + EPSV);
    }

    // ---- block reduction: sm/sq across 4 waves; lg lives wholly in wave 0 ----
    #pragma unroll
    for (int m = 1; m < 64; m <<= 1) {
        sm += __shfl_xor(sm, m);
        sq += __shfl_xor(sq, m);
        lg += __shfl_xor(lg, m);
    }
    const int w = tid >> 6;
    if ((tid & 63) == 0) { wred[w][0] = sm; wred[w][1] = sq; }
    __syncthreads();
    if (tid == 0) {
        float S = 0.f, Q = 0.f;
        #pragma unroll
        for (int i = 0; i < 4; ++i) { S += wred[i][0]; Q += wred[i][1]; }
        const float denom = (float)NN * (float)NN;
        const float contrib = SMOOTHR * S / denom
                            - DEGRR * lg / (float)NN
                            + SPARSR * Q / denom;
        atomicAdd(out + b, contrib);
    }
}

extern "C" void kernel_launch(void* const* d_in, const int* in_sizes, int n_in,
                              void* d_out, int out_size, void* d_ws, size_t ws_size,
                              hipStream_t stream) {
    const float* A = (const float*)d_in[0];   // out_adj [B,N,N]
    const float* F = (const float*)d_in[1];   // features [B,N,D]
    float* out = (float*)d_out;               // [B]

    const int B = out_size;                   // 64
    (void)hipMemsetAsync(d_out, 0, (size_t)B * sizeof(float), stream);
    graph_loss_kernel<<<dim3(B * (NN / ROWS)), dim3(TPB), 0, stream>>>(A, F, out);
}